// Round 7
// baseline (725.049 us; speedup 1.0000x reference)
//
#include <hip/hip_runtime.h>
#include <hip/hip_bf16.h>
#include <stdint.h>

// Problem constants
#define CIN   2304
#define HID_  512
#define NP    12544          // 256*49 output rows
#define OUT1  6422528        // 256*512*49

typedef float  f32x4 __attribute__((ext_vector_type(4)));
typedef short  s16x8 __attribute__((ext_vector_type(8)));

__device__ __forceinline__ uint16_t f2bf(float f) {
  uint32_t x = __builtin_bit_cast(uint32_t, f);
  return (uint16_t)((x + 0x7FFFu + ((x >> 16) & 1u)) >> 16);
}
__device__ __forceinline__ float bf2f(uint16_t u) {
  return __builtin_bit_cast(float, ((uint32_t)u) << 16);
}
__device__ __forceinline__ void gload16(const void* g, void* l) {
  __builtin_amdgcn_global_load_lds((const __attribute__((address_space(1))) void*)g,
                                   (__attribute__((address_space(3))) void*)l, 16, 0, 0);
}

// ---------------- merged prep: all four preps in one dispatch ----------------
// blocks [0,9216): prep_x   x(NCHW f32) -> xT[n'][c] bf16
// blocks [9216,18432): prep_w  conv_w -> Wt[t][o][c] bf16
// blocks [18432,18448): prep_A  A_i[j][e] = sum_d q1w[d][j]*k_w_i[d][e]
// blocks [18448,18576): prep_PVt  PVt_i[e][d] = sum_m p_w_i[d][m]*v_w_i[m][e]
__global__ __launch_bounds__(256) void prep_all_k(const float* __restrict__ xs,
    const float* __restrict__ cw, const float* __restrict__ q1w,
    const float* __restrict__ k1w, const float* __restrict__ k2w,
    const float* __restrict__ v1w, const float* __restrict__ v2w,
    const float* __restrict__ p1w, const float* __restrict__ p2w,
    uint16_t* __restrict__ xT, uint16_t* __restrict__ Wt,
    float* __restrict__ A, float* __restrict__ PVt) {
  __shared__ __align__(16) char sm[18448];
  const int tid = threadIdx.x;
  const int bi = blockIdx.x;
  if (bi < 9216) {                       // ---- prep_x ----
    float* t = (float*)sm;               // 3136 floats
    const int cg = bi % 36, b = bi / 36;
    const int c0 = cg * 64;
    const float4* src = (const float4*)(xs + ((size_t)b * CIN + c0) * 49);
    for (int i = tid; i < 784; i += 256) ((float4*)t)[i] = src[i];
    __syncthreads();
    for (int j = tid; j < 392; j += 256) {
      const int s = j >> 3, cq = j & 7;
      union { uint16_t us[8]; uint4 v; } pk;
#pragma unroll
      for (int q = 0; q < 8; ++q) pk.us[q] = f2bf(t[(cq * 8 + q) * 49 + s]);
      *(uint4*)(xT + ((size_t)(b * 49 + s) * CIN + c0 + cq * 8)) = pk.v;
    }
  } else if (bi < 18432) {               // ---- prep_w ([t][o][c] layout) ----
    float* t = (float*)sm;               // 1152 floats
    const int rest = bi - 9216;
    const int cg = rest % 18, o = rest / 18;
    const int c0 = cg * 128;
    const float* src = cw + ((size_t)o * CIN + c0) * 9;
    for (int i = tid; i < 1152; i += 256) t[i] = src[i];
    __syncthreads();
    if (tid < 144) {
      const int tp = tid >> 4, c8 = tid & 15;
      union { uint16_t us[8]; uint4 v; } pk;
#pragma unroll
      for (int q = 0; q < 8; ++q) pk.us[q] = f2bf(t[(c8 * 8 + q) * 9 + tp]);
      *(uint4*)(Wt + ((size_t)(tp * HID_ + o) * CIN + c0 + c8 * 8)) = pk.v;
    }
  } else if (bi < 18448) {               // ---- prep_A ----
    float* q1s = (float*)sm;                         // 3072 floats
    float (*red)[6][64] = (float(*)[6][64])(sm + 12288);
    const int rest = bi - 18432;
    const int e0 = (rest & 7) * 64, ib = rest >> 3;
    const int g = tid >> 6, l = tid & 63;
    for (int i = tid; i < 3072; i += 256) q1s[i] = q1w[i];
    __syncthreads();
    const float* kw = (ib ? k2w : k1w) + e0 + l;
    float acc[6] = {};
#pragma unroll 4
    for (int d = g * 128; d < (g + 1) * 128; ++d) {
      const float kv = kw[(size_t)d * 512];
#pragma unroll
      for (int j = 0; j < 6; ++j) acc[j] += q1s[d * 6 + j] * kv;
    }
#pragma unroll
    for (int j = 0; j < 6; ++j) red[g][j][l] = acc[j];
    __syncthreads();
    for (int i2 = tid; i2 < 384; i2 += 256) {
      const int j = i2 >> 6, l2 = i2 & 63;
      A[(ib * 6 + j) * 512 + e0 + l2] =
          red[0][j][l2] + red[1][j][l2] + red[2][j][l2] + red[3][j][l2];
    }
  } else {                               // ---- prep_PVt ----
    float* Av  = (float*)sm;             // 2048 floats
    float* Bpt = (float*)(sm + 8192);    // 2176 floats
    const int rest = bi - 18448;
    const int ibz = rest >> 6, r2 = rest & 63;
    const int d0 = (r2 & 7) * 64, e0 = (r2 >> 3) * 64;
    const float* vw = ibz ? v2w : v1w;
    const float* pw = ibz ? p2w : p1w;
    const int tx = tid & 15, ty = tid >> 4;
    float acc[4][4] = {};
    for (int m0 = 0; m0 < 512; m0 += 32) {
      __syncthreads();
      for (int i = tid; i < 2048; i += 256) {
        Av[i] = vw[(size_t)(m0 + (i >> 6)) * 512 + e0 + (i & 63)];
        Bpt[(i & 31) * 68 + (i >> 5)] = pw[(size_t)(d0 + (i >> 5)) * 512 + m0 + (i & 31)];
      }
      __syncthreads();
#pragma unroll 4
      for (int mm = 0; mm < 32; ++mm) {
        const float4 bv = *(const float4*)&Bpt[mm * 68 + tx * 4];
        const float4 av = *(const float4*)&Av[mm * 64 + ty * 4];
        const float a0[4] = {av.x, av.y, av.z, av.w};
        const float b0[4] = {bv.x, bv.y, bv.z, bv.w};
#pragma unroll
        for (int ee = 0; ee < 4; ++ee)
#pragma unroll
          for (int dd = 0; dd < 4; ++dd) acc[ee][dd] += a0[ee] * b0[dd];
      }
    }
#pragma unroll
    for (int ee = 0; ee < 4; ++ee) {
      float4 r; r.x = acc[ee][0]; r.y = acc[ee][1]; r.z = acc[ee][2]; r.w = acc[ee][3];
      *(float4*)&PVt[ibz * 262144 + (size_t)(e0 + ty * 4 + ee) * 512 + d0 + tx * 4] = r;
    }
  }
}

// ------------------------- conv as implicit-GEMM MFMA ------------------------
// D[n',o] = sum_{c,t} xT[n'+delta(t)][c] * Wt[t][o][c]  (masked at borders)
// Block: 128 rows x 128 o, 4 waves (2 row-halves x 2 o-halves), split-K=2.
// KEY this round: LDS <= 40KB -> 4 blocks/CU -> all 784 blocks co-resident
// (one dispatch round; kills the 2-round makespan quantization seen at
// 48KB/72KB).  W double-buffered per-tap (2x8KB), parity made compile-time
// by unrolling chunk PAIRS (9 taps/chunk -> parity flips per chunk).
// X halo [144 rows][80B] dbuf.  vmcnt(0)+barrier per tap (R3-proven cadence).
// LDS map: X0@0(11520) X1@11520 | W0@23040(8192) W1@31232 | Z@39424(16)
#define LDSX1  11520
#define LDSW   23040
#define LDSZ   39424
__global__ __launch_bounds__(256, 4) void conv_k(const uint16_t* __restrict__ xT,
    const uint16_t* __restrict__ Wt, uint16_t* __restrict__ feat0,
    uint16_t* __restrict__ feat1) {
  __shared__ __align__(16) char lds[39440];
  const int tid = threadIdx.x;
  const int wid = tid >> 6;
  const int lane = tid & 63;
  const int g16 = (lane >> 4) << 4;
  const int l15 = lane & 15;
  const int ww = wid & 1, wm = wid >> 1;

  const int idx = blockIdx.x;             // XCD = idx%8 = (bn*2+sp)
  const int sp = idx & 1;
  const int bn = (idx >> 1) & 3;
  const int bm = idx >> 3;
  const int n0 = bm * 128;
  const int o0 = bn * 128;
  const int c0 = sp * 36;                 // even for both sp -> chunk A = even

  // A-read base: LDS X row = wm*64 + m*16 + l15 + 8 (+tap shift), pitch 80
  const int rb0 = (wm * 64 + l15) * 80 + 640 + g16;
  int maskb[4];
#pragma unroll
  for (int m = 0; m < 4; ++m) {
    const int p = (n0 + wm * 64 + m * 16 + l15) % 49;
    const int y = p / 7, xx = p - y * 7;
    int mb = 0;
#pragma unroll
    for (int t = 0; t < 9; ++t) {
      const int yy = y + t / 3 - 1, xc = xx + t % 3 - 1;
      if (yy >= 0 && yy < 7 && xc >= 0 && xc < 7) mb |= 1 << t;
    }
    maskb[m] = mb;
  }

  // W-read base (swizzled); o row = ww*64 + n*16 + l15
  const int wb0 = ww * 4096 + l15 * 64 + (g16 ^ (((l15 >> 1) & 3) << 4));

  // W staging: 512 slots of 16B per tap, 2/thread, linear dest,
  // pre-swizzled source
  const char* WtB = (const char*)Wt;
  const char* xTB = (const char*)xT;
  int wsrc[2];
#pragma unroll
  for (int j = 0; j < 2; ++j) {
    const int slot = j * 256 + tid;
    const int row = slot >> 2, unit = slot & 3;
    const int lu = unit ^ ((row >> 1) & 3);
    wsrc[j] = (o0 + row) * 4608 + lu * 16;
  }
  // X staging: 720 slots (144 rows * 5 units of 16B, unit4 = pad dup), 3/thread
  int xsrc[3], xv[3];
#pragma unroll
  for (int k = 0; k < 3; ++k) {
    const int slot = k * 256 + tid;
    xv[k] = slot < 720;
    const int row = slot / 5;
    int unit = slot - row * 5; if (unit > 3) unit = 3;
    int nr = n0 - 8 + row;
    nr = nr < 0 ? 0 : (nr > NP - 1 ? NP - 1 : nr);   // clamped rows are masked
    xsrc[k] = nr * (CIN * 2) + unit * 16;
  }

  if (tid < 4) *(int*)(lds + LDSZ + tid * 4) = 0;
  __syncthreads();

#define XSTAGE(CC1) { \
    const char* xb_ = xTB + (size_t)(CC1) * 64; \
    char* xd_ = lds + ((CC1) & 1) * LDSX1 + wid * 1024; \
    if (xv[0]) gload16(xb_ + xsrc[0], xd_); \
    if (xv[1]) gload16(xb_ + xsrc[1], xd_ + 4096); \
    if (xv[2]) gload16(xb_ + xsrc[2], xd_ + 8192); }

// stage tap T of chunk CC into W buffer WB (8KB)
#define WSTAGE(T, CC, WB) { \
    const char* wb_ = WtB + (size_t)(T) * 2359296 + (size_t)(CC) * 64; \
    char* wd_ = lds + LDSW + (WB) * 8192 + wid * 1024; \
    gload16(wb_ + wsrc[0], wd_); \
    gload16(wb_ + wsrc[1], wd_ + 4096); }

// one tap: B-frags from W buffer WB, A-frags from X buf (XSEL)
#define TAP(TT, WB, XSEL) \
    { s16x8 bfr_[4]; \
      _Pragma("unroll") \
      for (int n_ = 0; n_ < 4; ++n_) \
        bfr_[n_] = *(const s16x8*)(lds + LDSW + (WB) * 8192 + wb0 + n_ * 1024); \
      __builtin_amdgcn_s_setprio(1); \
      _Pragma("unroll") \
      for (int m_ = 0; m_ < 4; ++m_) { \
        const int off_ = m_ * 1280 + (((TT) / 3 - 1) * 7 + ((TT) % 3 - 1)) * 80; \
        const int ab_ = ((maskb[m_] >> (TT)) & 1) ? (rb0 + (XSEL)) : (LDSZ - off_); \
        const s16x8 af_ = *(const s16x8*)(lds + ab_ + off_); \
        _Pragma("unroll") \
        for (int n_ = 0; n_ < 4; ++n_) \
          acc[m_][n_] = __builtin_amdgcn_mfma_f32_16x16x32_bf16(af_, bfr_[n_], acc[m_][n_], 0, 0, 0); \
      } \
      __builtin_amdgcn_s_setprio(0); }

#define SYNC \
    asm volatile("s_waitcnt vmcnt(0)" ::: "memory"); \
    __builtin_amdgcn_s_barrier(); \
    __builtin_amdgcn_sched_barrier(0);

  // prologue: X(c0) -> Xbuf0 (c0 even), W tap0 of c0 -> Wbuf0
  XSTAGE(c0);
  WSTAGE(0, c0, 0);
  f32x4 acc[4][4] = {};
  SYNC

#pragma unroll 1
  for (int i = 0; i < 18; ++i) {
    const int ccA = c0 + 2 * i, ccB = ccA + 1;
    // ---- chunk A (even): tap t reads Wbuf[t&1], X buf0 ----
    XSTAGE(ccB);
    WSTAGE(1, ccA, 1) TAP(0, 0, 0) SYNC
    WSTAGE(2, ccA, 0) TAP(1, 1, 0) SYNC
    WSTAGE(3, ccA, 1) TAP(2, 0, 0) SYNC
    WSTAGE(4, ccA, 0) TAP(3, 1, 0) SYNC
    WSTAGE(5, ccA, 1) TAP(4, 0, 0) SYNC
    WSTAGE(6, ccA, 0) TAP(5, 1, 0) SYNC
    WSTAGE(7, ccA, 1) TAP(6, 0, 0) SYNC
    WSTAGE(8, ccA, 0) TAP(7, 1, 0) SYNC
    WSTAGE(0, ccB, 1) TAP(8, 0, 0) SYNC
    // ---- chunk B (odd): tap t reads Wbuf[(t+1)&1], X buf1 ----
    if (i < 17) { XSTAGE(ccB + 1); }
    WSTAGE(1, ccB, 0) TAP(0, 1, LDSX1) SYNC
    WSTAGE(2, ccB, 1) TAP(1, 0, LDSX1) SYNC
    WSTAGE(3, ccB, 0) TAP(2, 1, LDSX1) SYNC
    WSTAGE(4, ccB, 1) TAP(3, 0, LDSX1) SYNC
    WSTAGE(5, ccB, 0) TAP(4, 1, LDSX1) SYNC
    WSTAGE(6, ccB, 1) TAP(5, 0, LDSX1) SYNC
    WSTAGE(7, ccB, 0) TAP(6, 1, LDSX1) SYNC
    WSTAGE(8, ccB, 1) TAP(7, 0, LDSX1) SYNC
    if (i < 17) { WSTAGE(0, ccB + 1, 0) }
    TAP(8, 1, LDSX1)
    SYNC
  }
#undef TAP
#undef WSTAGE
#undef XSTAGE
#undef SYNC

  // epilogue: C/D layout col=lane&15, row=4*(lane>>4)+reg; store bf16 partial
  uint16_t* fb = (sp ? feat1 : feat0) +
                 ((size_t)(n0 + wm * 64)) * HID_ + o0 + ww * 64;
  const int g4 = (lane >> 4) * 4;
#pragma unroll
  for (int m = 0; m < 4; ++m)
#pragma unroll
    for (int n = 0; n < 4; ++n)
#pragma unroll
      for (int r = 0; r < 4; ++r)
        fb[(m * 16 + g4 + r) * HID_ + n * 16 + l15] = f2bf(acc[m][n][r]);
}

// --------------- fused attention + projection + output epilogue --------------
#define FLP 520
__global__ __launch_bounds__(256) void att_k(const uint16_t* __restrict__ feat0,
    const uint16_t* __restrict__ feat1,
    const float* __restrict__ status, const float* __restrict__ rois,
    const float* __restrict__ A, const float* __restrict__ PVt,
    const float* __restrict__ pb1, const float* __restrict__ pb2,
    float* __restrict__ out) {
  __shared__ uint16_t fl[49 * FLP];
  __shared__ float qk[512];
  __shared__ float attv[64];
  __shared__ float fbar[512];
  __shared__ float v2[512];
  __shared__ float part[256];
  const int tid = threadIdx.x;
  const int b = blockIdx.x >> 1, ib = blockIdx.x & 1;

  // stage feat[b] = feat0[b]+feat1[b] (49x512) as bf16 in LDS
  const uint4* s0 = (const uint4*)(feat0 + (size_t)b * 25088);
  const uint4* s1 = (const uint4*)(feat1 + (size_t)b * 25088);
  for (int i = tid; i < 3136; i += 256) {
    const int n = i >> 6, e8 = (i & 63) << 3;
    union { uint16_t us[8]; uint4 v; } a, c, r;
    a.v = s0[i]; c.v = s1[i];
#pragma unroll
    for (int q = 0; q < 8; ++q) r.us[q] = f2bf(bf2f(a.us[q]) + bf2f(c.us[q]));
    *(uint4*)&fl[n * FLP + e8] = r.v;
  }
  // qk[e] = sum_j st6[j] * A_ib[j][e]
  float st6[6];
  st6[0] = status[b * 2]; st6[1] = status[b * 2 + 1];
#pragma unroll
  for (int j = 0; j < 4; ++j) st6[2 + j] = rois[b * 5 + 1 + j];
  for (int e = tid; e < 512; e += 256) {
    const float* Ai = A + ib * 3072;
    float s = 0.f;
#pragma unroll
    for (int j = 0; j < 6; ++j) s += st6[j] * Ai[j * 512 + e];
    qk[e] = s;
  }
  __syncthreads();

  // logits
  if (tid < 196) {
    const int n = tid >> 2;
    const int e0 = (tid & 3) * 128;
    float s = 0.f;
    for (int e = e0; e < e0 + 128; ++e) s += bf2f(fl[n * FLP + e]) * qk[e];
    part[tid] = s;
  }
  __syncthreads();
  if (tid < 64) {
    float l = -1e30f;
    if (tid < 49)
      l = 0.044194173824159216f *
          (part[tid * 4] + part[tid * 4 + 1] + part[tid * 4 + 2] + part[tid * 4 + 3]);
    float mx = l;
#pragma unroll
    for (int o = 32; o > 0; o >>= 1) mx = fmaxf(mx, __shfl_xor(mx, o, 64));
    const float ex = (tid < 49) ? __expf(l - mx) : 0.f;
    float sm = ex;
#pragma unroll
    for (int o = 32; o > 0; o >>= 1) sm += __shfl_xor(sm, o, 64);
    if (tid < 49) attv[tid] = ex / sm;
  }
  __syncthreads();
  // fbar[e] = sum_n att[n] * feat[n][e]
  for (int e = tid; e < 512; e += 256) {
    float s = 0.f;
#pragma unroll 7
    for (int n = 0; n < 49; ++n) s += attv[n] * bf2f(fl[n * FLP + e]);
    fbar[e] = s;
  }
  __syncthreads();
  // v2[d] = p_b[d] + sum_e PVt[e][d] * fbar[e]
  for (int d = tid; d < 512; d += 256) {
    const float* P = PVt + ib * 262144 + d;
    float s = (ib ? pb2 : pb1)[d];
#pragma unroll 8
    for (int e = 0; e < 512; ++e) s += P[(size_t)e * 512] * fbar[e];
    v2[d] = s;
  }
  __syncthreads();
  // out[b][c][p] = feat[p][c] + v2[c]   (coalesced writes)
  float* ob = out + (size_t)ib * OUT1 + (size_t)b * 25088;
  for (int w = tid; w < 25088; w += 256) {
    const int c = w / 49, p = w - c * 49;
    ob[w] = bf2f(fl[p * FLP + c]) + v2[c];
  }
}

extern "C" void kernel_launch(void* const* d_in, const int* in_sizes, int n_in,
                              void* d_out, int out_size, void* d_ws, size_t ws_size,
                              hipStream_t stream) {
  const float* status = (const float*)d_in[0];
  const float* rois   = (const float*)d_in[1];
  const float* bbox   = (const float*)d_in[2];
  const float* convw  = (const float*)d_in[3];
  const float* q1w    = (const float*)d_in[4];
  const float* k1w    = (const float*)d_in[5];
  const float* k2w    = (const float*)d_in[6];
  const float* v1w    = (const float*)d_in[7];
  const float* v2w    = (const float*)d_in[8];
  const float* p1w    = (const float*)d_in[9];
  const float* p1b    = (const float*)d_in[10];
  const float* p2w    = (const float*)d_in[11];
  const float* p2b    = (const float*)d_in[12];
  float* out = (float*)d_out;
  char* ws = (char*)d_ws;
  // ws layout (bytes): xT 57,802,752 | Wt 21,233,664 | feat0 12,845,056
  //                    | feat1 12,845,056 | PVt 2,097,152 | A 24,576
  //                    total 106,848,256 (== proven budget)
  uint16_t* xT    = (uint16_t*)(ws);
  uint16_t* Wt    = (uint16_t*)(ws + 57802752);
  uint16_t* feat0 = (uint16_t*)(ws + 79036416);
  uint16_t* feat1 = (uint16_t*)(ws + 91881472);
  float*    PVt   = (float*)(ws + 104726528);
  float*    A     = (float*)(ws + 106823680);
  if (ws_size < 106848256) return;  // insufficient scratch -> fail cleanly

  hipLaunchKernelGGL(prep_all_k, dim3(18576), dim3(256), 0, stream,
                     bbox, convw, q1w, k1w, k2w, v1w, v2w, p1w, p2w, xT, Wt, A, PVt);
  hipLaunchKernelGGL(conv_k, dim3(784), dim3(256), 0, stream, xT, Wt, feat0, feat1);
  hipLaunchKernelGGL(att_k,  dim3(512), dim3(256), 0, stream, feat0, feat1,
                     status, rois, A, PVt, p1b, p2b, out);
}

// Round 9
// 491.368 us; speedup vs baseline: 1.4756x; 1.4756x over previous
//
#include <hip/hip_runtime.h>
#include <hip/hip_bf16.h>
#include <stdint.h>

// Problem constants
#define CIN   2304
#define HID_  512
#define NP    12544          // 256*49 output rows
#define OUT1  6422528        // 256*512*49

typedef float  f32x4 __attribute__((ext_vector_type(4)));
typedef short  s16x8 __attribute__((ext_vector_type(8)));

__device__ __forceinline__ uint16_t f2bf(float f) {
  uint32_t x = __builtin_bit_cast(uint32_t, f);
  return (uint16_t)((x + 0x7FFFu + ((x >> 16) & 1u)) >> 16);
}
__device__ __forceinline__ float bf2f(uint16_t u) {
  return __builtin_bit_cast(float, ((uint32_t)u) << 16);
}
__device__ __forceinline__ void gload16(const void* g, void* l) {
  __builtin_amdgcn_global_load_lds((const __attribute__((address_space(1))) void*)g,
                                   (__attribute__((address_space(3))) void*)l, 16, 0, 0);
}

// --------- prep_x: x (NCHW f32) -> xT[n'=b*49+p][c] bf16, coalesced ---------
// block = (b, 288-channel chunk); writes are 576B-contiguous runs per row.
__global__ __launch_bounds__(256) void prep_x_k(const float* __restrict__ xs,
                                                uint16_t* __restrict__ xT) {
  __shared__ float t[288 * 49];          // 56448 B
  const int tid = threadIdx.x;
  const int b = blockIdx.x >> 3, cg = blockIdx.x & 7;
  const int c0 = cg * 288;
  const float4* src = (const float4*)(xs + ((size_t)b * CIN + c0) * 49);
  for (int i = tid; i < 3528; i += 256) ((float4*)t)[i] = src[i];
  __syncthreads();
  // tasks: 49 rows x 36 8-channel groups
  for (int j = tid; j < 1764; j += 256) {
    const int s = j / 36, u = j - s * 36;
    union { uint16_t us[8]; uint4 v; } pk;
#pragma unroll
    for (int q = 0; q < 8; ++q) pk.us[q] = f2bf(t[(u * 8 + q) * 49 + s]);
    *(uint4*)(xT + ((size_t)(b * 49 + s) * CIN + c0 + u * 8)) = pk.v;
  }
}

// --------- prep_rest: conv_w -> Wt[t][o][c] bf16 | A | PVt (merged) ----------
// blocks [0,9216): prep_w ; [9216,9232): prep_A ; [9232,9360): prep_PVt
__global__ __launch_bounds__(256) void prep_rest_k(const float* __restrict__ cw,
    const float* __restrict__ q1w,
    const float* __restrict__ k1w, const float* __restrict__ k2w,
    const float* __restrict__ v1w, const float* __restrict__ v2w,
    const float* __restrict__ p1w, const float* __restrict__ p2w,
    uint16_t* __restrict__ Wt, float* __restrict__ A, float* __restrict__ PVt) {
  __shared__ __align__(16) char sm[18448];
  const int tid = threadIdx.x;
  const int bi = blockIdx.x;
  if (bi < 9216) {                       // ---- prep_w ([t][o][c] layout) ----
    float* t = (float*)sm;               // 1152 floats
    const int cg = bi % 18, o = bi / 18;
    const int c0 = cg * 128;
    const float* src = cw + ((size_t)o * CIN + c0) * 9;
    for (int i = tid; i < 1152; i += 256) t[i] = src[i];
    __syncthreads();
    if (tid < 144) {
      const int tp = tid >> 4, c8 = tid & 15;
      union { uint16_t us[8]; uint4 v; } pk;
#pragma unroll
      for (int q = 0; q < 8; ++q) pk.us[q] = f2bf(t[(c8 * 8 + q) * 9 + tp]);
      *(uint4*)(Wt + ((size_t)(tp * HID_ + o) * CIN + c0 + c8 * 8)) = pk.v;
    }
  } else if (bi < 9232) {                // ---- prep_A ----
    float* q1s = (float*)sm;                         // 3072 floats
    float (*red)[6][64] = (float(*)[6][64])(sm + 12288);
    const int rest = bi - 9216;
    const int e0 = (rest & 7) * 64, ib = rest >> 3;
    const int g = tid >> 6, l = tid & 63;
    for (int i = tid; i < 3072; i += 256) q1s[i] = q1w[i];
    __syncthreads();
    const float* kw = (ib ? k2w : k1w) + e0 + l;
    float acc[6] = {};
#pragma unroll 4
    for (int d = g * 128; d < (g + 1) * 128; ++d) {
      const float kv = kw[(size_t)d * 512];
#pragma unroll
      for (int j = 0; j < 6; ++j) acc[j] += q1s[d * 6 + j] * kv;
    }
#pragma unroll
    for (int j = 0; j < 6; ++j) red[g][j][l] = acc[j];
    __syncthreads();
    for (int i2 = tid; i2 < 384; i2 += 256) {
      const int j = i2 >> 6, l2 = i2 & 63;
      A[(ib * 6 + j) * 512 + e0 + l2] =
          red[0][j][l2] + red[1][j][l2] + red[2][j][l2] + red[3][j][l2];
    }
  } else {                               // ---- prep_PVt ----
    float* Av  = (float*)sm;             // 2048 floats
    float* Bpt = (float*)(sm + 8192);    // 2176 floats
    const int rest = bi - 9232;
    const int ibz = rest >> 6, r2 = rest & 63;
    const int d0 = (r2 & 7) * 64, e0 = (r2 >> 3) * 64;
    const float* vw = ibz ? v2w : v1w;
    const float* pw = ibz ? p2w : p1w;
    const int tx = tid & 15, ty = tid >> 4;
    float acc[4][4] = {};
    for (int m0 = 0; m0 < 512; m0 += 32) {
      __syncthreads();
      for (int i = tid; i < 2048; i += 256) {
        Av[i] = vw[(size_t)(m0 + (i >> 6)) * 512 + e0 + (i & 63)];
        Bpt[(i & 31) * 68 + (i >> 5)] = pw[(size_t)(d0 + (i >> 5)) * 512 + m0 + (i & 31)];
      }
      __syncthreads();
#pragma unroll 4
      for (int mm = 0; mm < 32; ++mm) {
        const float4 bv = *(const float4*)&Bpt[mm * 68 + tx * 4];
        const float4 av = *(const float4*)&Av[mm * 64 + ty * 4];
        const float a0[4] = {av.x, av.y, av.z, av.w};
        const float b0[4] = {bv.x, bv.y, bv.z, bv.w};
#pragma unroll
        for (int ee = 0; ee < 4; ++ee)
#pragma unroll
          for (int dd = 0; dd < 4; ++dd) acc[ee][dd] += a0[ee] * b0[dd];
      }
    }
#pragma unroll
    for (int ee = 0; ee < 4; ++ee) {
      float4 r; r.x = acc[ee][0]; r.y = acc[ee][1]; r.z = acc[ee][2]; r.w = acc[ee][3];
      *(float4*)&PVt[ibz * 262144 + (size_t)(e0 + ty * 4 + ee) * 512 + d0 + tx * 4] = r;
    }
  }
}

// ------------------------- conv as implicit-GEMM MFMA ------------------------
// R3-PROVEN VERSION (294us, passed post-timing validation): 128x128 block,
// 4 waves (2 row-halves x 2 o-halves), split-K=2 -> feat0/feat1 bf16 partials.
// W tri-buffer (3x8KB, tap%3), X halo [144][80B] dbuf; counted-vmcnt cadence.
// LDS map: X0@0(11520) X1@11520 | W@23040 (3x8192) | Z@47616(16)
#define LDSX1  11520
#define LDSW   23040
#define LDSZ   47616
__global__ __launch_bounds__(256) void conv_k(const uint16_t* __restrict__ xT,
    const uint16_t* __restrict__ Wt, uint16_t* __restrict__ feat0,
    uint16_t* __restrict__ feat1) {
  __shared__ __align__(16) char lds[47632];
  const int tid = threadIdx.x;
  const int wid = tid >> 6;
  const int lane = tid & 63;
  const int g16 = (lane >> 4) << 4;
  const int l15 = lane & 15;
  const int ww = wid & 1, wm = wid >> 1;

  const int idx = blockIdx.x;             // XCD = idx%8 = (bn*2+sp)
  const int sp = idx & 1;
  const int bn = (idx >> 1) & 3;
  const int bm = idx >> 3;
  const int n0 = bm * 128;
  const int o0 = bn * 128;
  const int c0 = sp * 36;

  // A-read base: LDS X row = wm*64 + m*16 + l15 + 8 (+tap shift), pitch 80
  const int rb0 = (wm * 64 + l15) * 80 + 640 + g16;
  int maskb[4];
#pragma unroll
  for (int m = 0; m < 4; ++m) {
    const int p = (n0 + wm * 64 + m * 16 + l15) % 49;
    const int y = p / 7, xx = p - y * 7;
    int mb = 0;
#pragma unroll
    for (int t = 0; t < 9; ++t) {
      const int yy = y + t / 3 - 1, xc = xx + t % 3 - 1;
      if (yy >= 0 && yy < 7 && xc >= 0 && xc < 7) mb |= 1 << t;
    }
    maskb[m] = mb;
  }

  // W-read base (swizzled); o row = ww*64 + n*16 + l15
  const int wb0 = ww * 4096 + l15 * 64 + (g16 ^ (((l15 >> 1) & 3) << 4));

  // W staging: 512 slots of 16B, 2/thread, linear dest, pre-swizzled source
  const char* WtB = (const char*)Wt;
  const char* xTB = (const char*)xT;
  int wsrc[2];
  const int wdstb = wid * 1024;
#pragma unroll
  for (int j = 0; j < 2; ++j) {
    const int slot = j * 256 + tid;
    const int row = slot >> 2, unit = slot & 3;
    const int lu = unit ^ ((row >> 1) & 3);
    wsrc[j] = (o0 + row) * (CIN * 2) + lu * 16;
  }
  // X staging: 720 slots (144 rows * 5 units of 16B, unit4 = pad dup), 3/thread
  int xsrc[3], xv[3];
#pragma unroll
  for (int k = 0; k < 3; ++k) {
    const int slot = k * 256 + tid;
    xv[k] = slot < 720;
    const int row = slot / 5;
    int unit = slot - row * 5; if (unit > 3) unit = 3;
    int nr = n0 - 8 + row;
    nr = nr < 0 ? 0 : (nr > NP - 1 ? NP - 1 : nr);   // clamped rows are masked
    xsrc[k] = nr * (CIN * 2) + unit * 16;
  }

  if (tid < 4) *(int*)(lds + LDSZ + tid * 4) = 0;
  __syncthreads();

  // prologue queue per wave: X(c0):3, W(t0):2, W(t1):2  -> 7 outstanding
  {
    const char* xb = xTB + (size_t)c0 * 64;
    if (xv[0]) gload16(xb + xsrc[0], lds + wdstb);
    if (xv[1]) gload16(xb + xsrc[1], lds + 4096 + wdstb);
    if (xv[2]) gload16(xb + xsrc[2], lds + 8192 + wdstb);
    const char* wp0 = WtB + (size_t)c0 * 64;
    gload16(wp0 + wsrc[0], lds + LDSW + wdstb);
    gload16(wp0 + wsrc[1], lds + LDSW + 4096 + wdstb);
    const char* wp1 = WtB + 2359296 + (size_t)c0 * 64;
    gload16(wp1 + wsrc[0], lds + LDSW + 8192 + wdstb);
    gload16(wp1 + wsrc[1], lds + LDSW + 8192 + 4096 + wdstb);
  }

  f32x4 acc[4][4] = {};

#define WISS(TTN, CCO) { \
    const char* wb_ = WtB + (size_t)(TTN) * 2359296 + (size_t)(cc + (CCO)) * 64; \
    const int wo_ = LDSW + ((TTN) % 3) * 8192 + wdstb; \
    gload16(wb_ + wsrc[0], lds + wo_); \
    gload16(wb_ + wsrc[1], lds + wo_ + 4096); }

#define XISS { \
    const char* xb_ = xTB + (size_t)(cc + 1) * 64; \
    const int xo_ = ((cc + 1) & 1) * 11520 + wdstb; \
    if (xv[0]) gload16(xb_ + xsrc[0], lds + xo_); \
    if (xv[1]) gload16(xb_ + xsrc[1], lds + xo_ + 4096); \
    if (xv[2]) gload16(xb_ + xsrc[2], lds + xo_ + 8192); }

#define TAP(TT, VM, ISSUES) \
    asm volatile("s_waitcnt vmcnt(" VM ")" ::: "memory"); \
    __builtin_amdgcn_s_barrier(); \
    __builtin_amdgcn_sched_barrier(0); \
    ISSUES \
    { \
      const int wof_ = LDSW + ((TT) % 3) * 8192; \
      s16x8 bfr_[4]; \
      _Pragma("unroll") \
      for (int n_ = 0; n_ < 4; ++n_) \
        bfr_[n_] = *(const s16x8*)(lds + wof_ + wb0 + n_ * 1024); \
      __builtin_amdgcn_s_setprio(1); \
      _Pragma("unroll") \
      for (int m_ = 0; m_ < 4; ++m_) { \
        const int off_ = m_ * 1280 + (((TT) / 3 - 1) * 7 + ((TT) % 3 - 1)) * 80; \
        const int ab_ = ((maskb[m_] >> (TT)) & 1) ? (rb0 + xsel) : (LDSZ - off_); \
        const s16x8 af_ = *(const s16x8*)(lds + ab_ + off_); \
        _Pragma("unroll") \
        for (int n_ = 0; n_ < 4; ++n_) \
          acc[m_][n_] = __builtin_amdgcn_mfma_f32_16x16x32_bf16(af_, bfr_[n_], acc[m_][n_], 0, 0, 0); \
      } \
      __builtin_amdgcn_s_setprio(0); \
    }

#pragma unroll 1
  for (int cc = c0; cc < c0 + 35; ++cc) {
    const int xsel = (cc & 1) * 11520;
    TAP(0, "2", WISS(2, 0) XISS)
    TAP(1, "5", WISS(3, 0))
    TAP(2, "5", WISS(4, 0))
    TAP(3, "2", WISS(5, 0))
    TAP(4, "2", WISS(6, 0))
    TAP(5, "2", WISS(7, 0))
    TAP(6, "2", WISS(8, 0))
    TAP(7, "2", WISS(0, 1))
    TAP(8, "2", WISS(1, 1))
  }
  {
    const int cc = c0 + 35;
    const int xsel = (cc & 1) * 11520;
    TAP(0, "2", WISS(2, 0))
    TAP(1, "2", WISS(3, 0))
    TAP(2, "2", WISS(4, 0))
    TAP(3, "2", WISS(5, 0))
    TAP(4, "2", WISS(6, 0))
    TAP(5, "2", WISS(7, 0))
    TAP(6, "2", WISS(8, 0))
    TAP(7, "2", )
    TAP(8, "0", )
  }
#undef TAP
#undef WISS
#undef XISS

  // epilogue: C/D layout col=lane&15, row=4*(lane>>4)+reg; store bf16 partial
  uint16_t* fb = (sp ? feat1 : feat0) +
                 ((size_t)(n0 + wm * 64)) * HID_ + o0 + ww * 64;
  const int g4 = (lane >> 4) * 4;
#pragma unroll
  for (int m = 0; m < 4; ++m)
#pragma unroll
    for (int n = 0; n < 4; ++n)
#pragma unroll
      for (int r = 0; r < 4; ++r)
        fb[(m * 16 + g4 + r) * HID_ + n * 16 + l15] = f2bf(acc[m][n][r]);
}

// --------------- fused attention + projection + output epilogue --------------
#define FLP 520
__global__ __launch_bounds__(256) void att_k(const uint16_t* __restrict__ feat0,
    const uint16_t* __restrict__ feat1,
    const float* __restrict__ status, const float* __restrict__ rois,
    const float* __restrict__ A, const float* __restrict__ PVt,
    const float* __restrict__ pb1, const float* __restrict__ pb2,
    float* __restrict__ out) {
  __shared__ uint16_t fl[49 * FLP];
  __shared__ float qk[512];
  __shared__ float attv[64];
  __shared__ float fbar[512];
  __shared__ float v2[512];
  __shared__ float part[256];
  const int tid = threadIdx.x;
  const int b = blockIdx.x >> 1, ib = blockIdx.x & 1;

  // stage feat[b] = feat0[b]+feat1[b] (49x512) as bf16 in LDS
  const uint4* s0 = (const uint4*)(feat0 + (size_t)b * 25088);
  const uint4* s1 = (const uint4*)(feat1 + (size_t)b * 25088);
  for (int i = tid; i < 3136; i += 256) {
    const int n = i >> 6, e8 = (i & 63) << 3;
    union { uint16_t us[8]; uint4 v; } a, c, r;
    a.v = s0[i]; c.v = s1[i];
#pragma unroll
    for (int q = 0; q < 8; ++q) r.us[q] = f2bf(bf2f(a.us[q]) + bf2f(c.us[q]));
    *(uint4*)&fl[n * FLP + e8] = r.v;
  }
  // qk[e] = sum_j st6[j] * A_ib[j][e]
  float st6[6];
  st6[0] = status[b * 2]; st6[1] = status[b * 2 + 1];
#pragma unroll
  for (int j = 0; j < 4; ++j) st6[2 + j] = rois[b * 5 + 1 + j];
  for (int e = tid; e < 512; e += 256) {
    const float* Ai = A + ib * 3072;
    float s = 0.f;
#pragma unroll
    for (int j = 0; j < 6; ++j) s += st6[j] * Ai[j * 512 + e];
    qk[e] = s;
  }
  __syncthreads();

  // logits
  if (tid < 196) {
    const int n = tid >> 2;
    const int e0 = (tid & 3) * 128;
    float s = 0.f;
    for (int e = e0; e < e0 + 128; ++e) s += bf2f(fl[n * FLP + e]) * qk[e];
    part[tid] = s;
  }
  __syncthreads();
  if (tid < 64) {
    float l = -1e30f;
    if (tid < 49)
      l = 0.044194173824159216f *
          (part[tid * 4] + part[tid * 4 + 1] + part[tid * 4 + 2] + part[tid * 4 + 3]);
    float mx = l;
#pragma unroll
    for (int o = 32; o > 0; o >>= 1) mx = fmaxf(mx, __shfl_xor(mx, o, 64));
    const float ex = (tid < 49) ? __expf(l - mx) : 0.f;
    float sm = ex;
#pragma unroll
    for (int o = 32; o > 0; o >>= 1) sm += __shfl_xor(sm, o, 64);
    if (tid < 49) attv[tid] = ex / sm;
  }
  __syncthreads();
  // fbar[e] = sum_n att[n] * feat[n][e]
  for (int e = tid; e < 512; e += 256) {
    float s = 0.f;
#pragma unroll 7
    for (int n = 0; n < 49; ++n) s += attv[n] * bf2f(fl[n * FLP + e]);
    fbar[e] = s;
  }
  __syncthreads();
  // v2[d] = p_b[d] + sum_e PVt[e][d] * fbar[e]
  for (int d = tid; d < 512; d += 256) {
    const float* P = PVt + ib * 262144 + d;
    float s = (ib ? pb2 : pb1)[d];
#pragma unroll 8
    for (int e = 0; e < 512; ++e) s += P[(size_t)e * 512] * fbar[e];
    v2[d] = s;
  }
  __syncthreads();
  // out[b][c][p] = feat[p][c] + v2[c]   (coalesced writes)
  float* ob = out + (size_t)ib * OUT1 + (size_t)b * 25088;
  for (int w = tid; w < 25088; w += 256) {
    const int c = w / 49, p = w - c * 49;
    ob[w] = bf2f(fl[p * FLP + c]) + v2[c];
  }
}

extern "C" void kernel_launch(void* const* d_in, const int* in_sizes, int n_in,
                              void* d_out, int out_size, void* d_ws, size_t ws_size,
                              hipStream_t stream) {
  const float* status = (const float*)d_in[0];
  const float* rois   = (const float*)d_in[1];
  const float* bbox   = (const float*)d_in[2];
  const float* convw  = (const float*)d_in[3];
  const float* q1w    = (const float*)d_in[4];
  const float* k1w    = (const float*)d_in[5];
  const float* k2w    = (const float*)d_in[6];
  const float* v1w    = (const float*)d_in[7];
  const float* v2w    = (const float*)d_in[8];
  const float* p1w    = (const float*)d_in[9];
  const float* p1b    = (const float*)d_in[10];
  const float* p2w    = (const float*)d_in[11];
  const float* p2b    = (const float*)d_in[12];
  float* out = (float*)d_out;
  char* ws = (char*)d_ws;
  // ws layout (bytes): xT 57,802,752 | Wt 21,233,664 | feat0 12,845,056
  //                    | feat1 12,845,056 | PVt 2,097,152 | A 24,576
  //                    total 106,848,256 (== proven budget)
  uint16_t* xT    = (uint16_t*)(ws);
  uint16_t* Wt    = (uint16_t*)(ws + 57802752);
  uint16_t* feat0 = (uint16_t*)(ws + 79036416);
  uint16_t* feat1 = (uint16_t*)(ws + 91881472);
  float*    PVt   = (float*)(ws + 104726528);
  float*    A     = (float*)(ws + 106823680);
  if (ws_size < 106848256) return;  // insufficient scratch -> fail cleanly

  hipLaunchKernelGGL(prep_x_k,    dim3(2048), dim3(256), 0, stream, bbox, xT);
  hipLaunchKernelGGL(prep_rest_k, dim3(9360), dim3(256), 0, stream,
                     convw, q1w, k1w, k2w, v1w, v2w, p1w, p2w, Wt, A, PVt);
  hipLaunchKernelGGL(conv_k, dim3(784), dim3(256), 0, stream, xT, Wt, feat0, feat1);
  hipLaunchKernelGGL(att_k,  dim3(512), dim3(256), 0, stream, feat0, feat1,
                     status, rois, A, PVt, p1b, p2b, out);
}

// Round 10
// 405.520 us; speedup vs baseline: 1.7879x; 1.2117x over previous
//
#include <hip/hip_runtime.h>
#include <hip/hip_bf16.h>
#include <stdint.h>

// Problem constants
#define CIN   2304
#define HID_  512
#define NP    12544          // 256*49 output rows
#define OUT1  6422528        // 256*512*49

typedef float  f32x4 __attribute__((ext_vector_type(4)));
typedef short  s16x8 __attribute__((ext_vector_type(8)));

__device__ __forceinline__ uint16_t f2bf(float f) {
  uint32_t x = __builtin_bit_cast(uint32_t, f);
  return (uint16_t)((x + 0x7FFFu + ((x >> 16) & 1u)) >> 16);
}
__device__ __forceinline__ float bf2f(uint16_t u) {
  return __builtin_bit_cast(float, ((uint32_t)u) << 16);
}
__device__ __forceinline__ void gload16(const void* g, void* l) {
  __builtin_amdgcn_global_load_lds((const __attribute__((address_space(1))) void*)g,
                                   (__attribute__((address_space(3))) void*)l, 16, 0, 0);
}

// ---------------- prep1: xT and Wt transposes in one dispatch ----------------
// blocks [0,9216): prep_x   x(NCHW f32) -> xT[n'][c] bf16  (R6-proven body)
// blocks [9216,18432): prep_w  conv_w -> Wt[t][o][c] bf16  (R6-proven body)
__global__ __launch_bounds__(256) void prep1_k(const float* __restrict__ xs,
    const float* __restrict__ cw,
    uint16_t* __restrict__ xT, uint16_t* __restrict__ Wt) {
  __shared__ __align__(16) char sm[12800];
  const int tid = threadIdx.x;
  const int bi = blockIdx.x;
  if (bi < 9216) {                       // ---- prep_x ----
    float* t = (float*)sm;               // 3136 floats
    const int cg = bi % 36, b = bi / 36;
    const int c0 = cg * 64;
    const float4* src = (const float4*)(xs + ((size_t)b * CIN + c0) * 49);
    for (int i = tid; i < 784; i += 256) ((float4*)t)[i] = src[i];
    __syncthreads();
    for (int j = tid; j < 392; j += 256) {
      const int s = j >> 3, cq = j & 7;
      union { uint16_t us[8]; uint4 v; } pk;
#pragma unroll
      for (int q = 0; q < 8; ++q) pk.us[q] = f2bf(t[(cq * 8 + q) * 49 + s]);
      *(uint4*)(xT + ((size_t)(b * 49 + s) * CIN + c0 + cq * 8)) = pk.v;
    }
  } else {                               // ---- prep_w ([t][o][c] layout) ----
    float* t = (float*)sm;               // 1152 floats
    const int rest = bi - 9216;
    const int cg = rest % 18, o = rest / 18;
    const int c0 = cg * 128;
    const float* src = cw + ((size_t)o * CIN + c0) * 9;
    for (int i = tid; i < 1152; i += 256) t[i] = src[i];
    __syncthreads();
    if (tid < 144) {
      const int tp = tid >> 4, c8 = tid & 15;
      union { uint16_t us[8]; uint4 v; } pk;
#pragma unroll
      for (int q = 0; q < 8; ++q) pk.us[q] = f2bf(t[(c8 * 8 + q) * 9 + tp]);
      *(uint4*)(Wt + ((size_t)(tp * HID_ + o) * CIN + c0 + c8 * 8)) = pk.v;
    }
  }
}

// ------- tail blocks of the conv dispatch: prep_A (16) + prep_PVt (128) ------
__device__ __forceinline__ void prep_tail(int rest, int tid, char* sm,
    const float* __restrict__ q1w,
    const float* __restrict__ k1w, const float* __restrict__ k2w,
    const float* __restrict__ v1w, const float* __restrict__ v2w,
    const float* __restrict__ p1w, const float* __restrict__ p2w,
    float* __restrict__ A, float* __restrict__ PVt) {
  if (rest < 16) {                       // ---- prep_A ----
    float* q1s = (float*)sm;                         // 3072 floats
    float (*red)[6][64] = (float(*)[6][64])(sm + 12288);
    const int e0 = (rest & 7) * 64, ib = rest >> 3;
    const int g = tid >> 6, l = tid & 63;
    for (int i = tid; i < 3072; i += 256) q1s[i] = q1w[i];
    __syncthreads();
    const float* kw = (ib ? k2w : k1w) + e0 + l;
    float acc[6] = {};
#pragma unroll 4
    for (int d = g * 128; d < (g + 1) * 128; ++d) {
      const float kv = kw[(size_t)d * 512];
#pragma unroll
      for (int j = 0; j < 6; ++j) acc[j] += q1s[d * 6 + j] * kv;
    }
#pragma unroll
    for (int j = 0; j < 6; ++j) red[g][j][l] = acc[j];
    __syncthreads();
    for (int i2 = tid; i2 < 384; i2 += 256) {
      const int j = i2 >> 6, l2 = i2 & 63;
      A[(ib * 6 + j) * 512 + e0 + l2] =
          red[0][j][l2] + red[1][j][l2] + red[2][j][l2] + red[3][j][l2];
    }
  } else {                               // ---- prep_PVt ----
    float* Av  = (float*)sm;             // 2048 floats
    float* Bpt = (float*)(sm + 8192);    // 2176 floats
    const int r0 = rest - 16;
    const int ibz = r0 >> 6, r2 = r0 & 63;
    const int d0 = (r2 & 7) * 64, e0 = (r2 >> 3) * 64;
    const float* vw = ibz ? v2w : v1w;
    const float* pw = ibz ? p2w : p1w;
    const int tx = tid & 15, ty = tid >> 4;
    float acc[4][4] = {};
    for (int m0 = 0; m0 < 512; m0 += 32) {
      __syncthreads();
      for (int i = tid; i < 2048; i += 256) {
        Av[i] = vw[(size_t)(m0 + (i >> 6)) * 512 + e0 + (i & 63)];
        Bpt[(i & 31) * 68 + (i >> 5)] = pw[(size_t)(d0 + (i >> 5)) * 512 + m0 + (i & 31)];
      }
      __syncthreads();
#pragma unroll 4
      for (int mm = 0; mm < 32; ++mm) {
        const float4 bv = *(const float4*)&Bpt[mm * 68 + tx * 4];
        const float4 av = *(const float4*)&Av[mm * 64 + ty * 4];
        const float a0[4] = {av.x, av.y, av.z, av.w};
        const float b0[4] = {bv.x, bv.y, bv.z, bv.w};
#pragma unroll
        for (int ee = 0; ee < 4; ++ee)
#pragma unroll
          for (int dd = 0; dd < 4; ++dd) acc[ee][dd] += a0[ee] * b0[dd];
      }
    }
#pragma unroll
    for (int ee = 0; ee < 4; ++ee) {
      float4 r; r.x = acc[ee][0]; r.y = acc[ee][1]; r.z = acc[ee][2]; r.w = acc[ee][3];
      *(float4*)&PVt[ibz * 262144 + (size_t)(e0 + ty * 4 + ee) * 512 + d0 + tx * 4] = r;
    }
  }
}

// ------------------------- conv as implicit-GEMM MFMA ------------------------
// blocks [0,784): R3-PROVEN conv body (294us, twice-validated).
// blocks [784,928): prep_A / prep_PVt tail (independent of conv; hides in
// conv's shadow, saving one dispatch + ~12us of serial GEMM time).
// LDS map (conv): X0@0(11520) X1@11520 | W@23040 (3x8192) | Z@47616(16)
#define LDSX1  11520
#define LDSW   23040
#define LDSZ   47616
__global__ __launch_bounds__(256) void conv_k(const uint16_t* __restrict__ xT,
    const uint16_t* __restrict__ Wt, uint16_t* __restrict__ feat0,
    uint16_t* __restrict__ feat1,
    const float* __restrict__ q1w,
    const float* __restrict__ k1w, const float* __restrict__ k2w,
    const float* __restrict__ v1w, const float* __restrict__ v2w,
    const float* __restrict__ p1w, const float* __restrict__ p2w,
    float* __restrict__ A, float* __restrict__ PVt) {
  __shared__ __align__(16) char lds[47632];
  const int tid = threadIdx.x;
  const int bidx = blockIdx.x;
  if (bidx >= 784) {
    prep_tail(bidx - 784, tid, lds, q1w, k1w, k2w, v1w, v2w, p1w, p2w, A, PVt);
    return;
  }
  const int wid = tid >> 6;
  const int lane = tid & 63;
  const int g16 = (lane >> 4) << 4;
  const int l15 = lane & 15;
  const int ww = wid & 1, wm = wid >> 1;

  const int idx = bidx;                   // XCD = idx%8 = (bn*2+sp)
  const int sp = idx & 1;
  const int bn = (idx >> 1) & 3;
  const int bm = idx >> 3;
  const int n0 = bm * 128;
  const int o0 = bn * 128;
  const int c0 = sp * 36;

  // A-read base: LDS X row = wm*64 + m*16 + l15 + 8 (+tap shift), pitch 80
  const int rb0 = (wm * 64 + l15) * 80 + 640 + g16;
  int maskb[4];
#pragma unroll
  for (int m = 0; m < 4; ++m) {
    const int p = (n0 + wm * 64 + m * 16 + l15) % 49;
    const int y = p / 7, xx = p - y * 7;
    int mb = 0;
#pragma unroll
    for (int t = 0; t < 9; ++t) {
      const int yy = y + t / 3 - 1, xc = xx + t % 3 - 1;
      if (yy >= 0 && yy < 7 && xc >= 0 && xc < 7) mb |= 1 << t;
    }
    maskb[m] = mb;
  }

  // W-read base (swizzled); o row = ww*64 + n*16 + l15
  const int wb0 = ww * 4096 + l15 * 64 + (g16 ^ (((l15 >> 1) & 3) << 4));

  // W staging: 512 slots of 16B, 2/thread, linear dest, pre-swizzled source
  const char* WtB = (const char*)Wt;
  const char* xTB = (const char*)xT;
  int wsrc[2];
  const int wdstb = wid * 1024;
#pragma unroll
  for (int j = 0; j < 2; ++j) {
    const int slot = j * 256 + tid;
    const int row = slot >> 2, unit = slot & 3;
    const int lu = unit ^ ((row >> 1) & 3);
    wsrc[j] = (o0 + row) * (CIN * 2) + lu * 16;
  }
  // X staging: 720 slots (144 rows * 5 units of 16B, unit4 = pad dup), 3/thread
  int xsrc[3], xv[3];
#pragma unroll
  for (int k = 0; k < 3; ++k) {
    const int slot = k * 256 + tid;
    xv[k] = slot < 720;
    const int row = slot / 5;
    int unit = slot - row * 5; if (unit > 3) unit = 3;
    int nr = n0 - 8 + row;
    nr = nr < 0 ? 0 : (nr > NP - 1 ? NP - 1 : nr);   // clamped rows are masked
    xsrc[k] = nr * (CIN * 2) + unit * 16;
  }

  if (tid < 4) *(int*)(lds + LDSZ + tid * 4) = 0;
  __syncthreads();

  // prologue queue per wave: X(c0):3, W(t0):2, W(t1):2  -> 7 outstanding
  {
    const char* xb = xTB + (size_t)c0 * 64;
    if (xv[0]) gload16(xb + xsrc[0], lds + wdstb);
    if (xv[1]) gload16(xb + xsrc[1], lds + 4096 + wdstb);
    if (xv[2]) gload16(xb + xsrc[2], lds + 8192 + wdstb);
    const char* wp0 = WtB + (size_t)c0 * 64;
    gload16(wp0 + wsrc[0], lds + LDSW + wdstb);
    gload16(wp0 + wsrc[1], lds + LDSW + 4096 + wdstb);
    const char* wp1 = WtB + 2359296 + (size_t)c0 * 64;
    gload16(wp1 + wsrc[0], lds + LDSW + 8192 + wdstb);
    gload16(wp1 + wsrc[1], lds + LDSW + 8192 + 4096 + wdstb);
  }

  f32x4 acc[4][4] = {};

#define WISS(TTN, CCO) { \
    const char* wb_ = WtB + (size_t)(TTN) * 2359296 + (size_t)(cc + (CCO)) * 64; \
    const int wo_ = LDSW + ((TTN) % 3) * 8192 + wdstb; \
    gload16(wb_ + wsrc[0], lds + wo_); \
    gload16(wb_ + wsrc[1], lds + wo_ + 4096); }

#define XISS { \
    const char* xb_ = xTB + (size_t)(cc + 1) * 64; \
    const int xo_ = ((cc + 1) & 1) * 11520 + wdstb; \
    if (xv[0]) gload16(xb_ + xsrc[0], lds + xo_); \
    if (xv[1]) gload16(xb_ + xsrc[1], lds + xo_ + 4096); \
    if (xv[2]) gload16(xb_ + xsrc[2], lds + xo_ + 8192); }

#define TAP(TT, VM, ISSUES) \
    asm volatile("s_waitcnt vmcnt(" VM ")" ::: "memory"); \
    __builtin_amdgcn_s_barrier(); \
    __builtin_amdgcn_sched_barrier(0); \
    ISSUES \
    { \
      const int wof_ = LDSW + ((TT) % 3) * 8192; \
      s16x8 bfr_[4]; \
      _Pragma("unroll") \
      for (int n_ = 0; n_ < 4; ++n_) \
        bfr_[n_] = *(const s16x8*)(lds + wof_ + wb0 + n_ * 1024); \
      __builtin_amdgcn_s_setprio(1); \
      _Pragma("unroll") \
      for (int m_ = 0; m_ < 4; ++m_) { \
        const int off_ = m_ * 1280 + (((TT) / 3 - 1) * 7 + ((TT) % 3 - 1)) * 80; \
        const int ab_ = ((maskb[m_] >> (TT)) & 1) ? (rb0 + xsel) : (LDSZ - off_); \
        const s16x8 af_ = *(const s16x8*)(lds + ab_ + off_); \
        _Pragma("unroll") \
        for (int n_ = 0; n_ < 4; ++n_) \
          acc[m_][n_] = __builtin_amdgcn_mfma_f32_16x16x32_bf16(af_, bfr_[n_], acc[m_][n_], 0, 0, 0); \
      } \
      __builtin_amdgcn_s_setprio(0); \
    }

#pragma unroll 1
  for (int cc = c0; cc < c0 + 35; ++cc) {
    const int xsel = (cc & 1) * 11520;
    TAP(0, "2", WISS(2, 0) XISS)
    TAP(1, "5", WISS(3, 0))
    TAP(2, "5", WISS(4, 0))
    TAP(3, "2", WISS(5, 0))
    TAP(4, "2", WISS(6, 0))
    TAP(5, "2", WISS(7, 0))
    TAP(6, "2", WISS(8, 0))
    TAP(7, "2", WISS(0, 1))
    TAP(8, "2", WISS(1, 1))
  }
  {
    const int cc = c0 + 35;
    const int xsel = (cc & 1) * 11520;
    TAP(0, "2", WISS(2, 0))
    TAP(1, "2", WISS(3, 0))
    TAP(2, "2", WISS(4, 0))
    TAP(3, "2", WISS(5, 0))
    TAP(4, "2", WISS(6, 0))
    TAP(5, "2", WISS(7, 0))
    TAP(6, "2", WISS(8, 0))
    TAP(7, "2", )
    TAP(8, "0", )
  }
#undef TAP
#undef WISS
#undef XISS

  // epilogue: C/D layout col=lane&15, row=4*(lane>>4)+reg; store bf16 partial
  uint16_t* fb = (sp ? feat1 : feat0) +
                 ((size_t)(n0 + wm * 64)) * HID_ + o0 + ww * 64;
  const int g4 = (lane >> 4) * 4;
#pragma unroll
  for (int m = 0; m < 4; ++m)
#pragma unroll
    for (int n = 0; n < 4; ++n)
#pragma unroll
      for (int r = 0; r < 4; ++r)
        fb[(m * 16 + g4 + r) * HID_ + n * 16 + l15] = f2bf(acc[m][n][r]);
}

// --------------- fused attention + projection + output epilogue --------------
#define FLP 520
__global__ __launch_bounds__(256) void att_k(const uint16_t* __restrict__ feat0,
    const uint16_t* __restrict__ feat1,
    const float* __restrict__ status, const float* __restrict__ rois,
    const float* __restrict__ A, const float* __restrict__ PVt,
    const float* __restrict__ pb1, const float* __restrict__ pb2,
    float* __restrict__ out) {
  __shared__ uint16_t fl[49 * FLP];
  __shared__ float qk[512];
  __shared__ float attv[64];
  __shared__ float fbar[512];
  __shared__ float v2[512];
  __shared__ float part[256];
  const int tid = threadIdx.x;
  const int b = blockIdx.x >> 1, ib = blockIdx.x & 1;

  // stage feat[b] = feat0[b]+feat1[b] (49x512) as bf16 in LDS
  const uint4* s0 = (const uint4*)(feat0 + (size_t)b * 25088);
  const uint4* s1 = (const uint4*)(feat1 + (size_t)b * 25088);
  for (int i = tid; i < 3136; i += 256) {
    const int n = i >> 6, e8 = (i & 63) << 3;
    union { uint16_t us[8]; uint4 v; } a, c, r;
    a.v = s0[i]; c.v = s1[i];
#pragma unroll
    for (int q = 0; q < 8; ++q) r.us[q] = f2bf(bf2f(a.us[q]) + bf2f(c.us[q]));
    *(uint4*)&fl[n * FLP + e8] = r.v;
  }
  // qk[e] = sum_j st6[j] * A_ib[j][e]
  float st6[6];
  st6[0] = status[b * 2]; st6[1] = status[b * 2 + 1];
#pragma unroll
  for (int j = 0; j < 4; ++j) st6[2 + j] = rois[b * 5 + 1 + j];
  for (int e = tid; e < 512; e += 256) {
    const float* Ai = A + ib * 3072;
    float s = 0.f;
#pragma unroll
    for (int j = 0; j < 6; ++j) s += st6[j] * Ai[j * 512 + e];
    qk[e] = s;
  }
  __syncthreads();

  // logits (vectorized: bf16x8 via uint4)
  if (tid < 196) {
    const int n = tid >> 2;
    const int e0 = (tid & 3) * 128;
    float s = 0.f;
#pragma unroll 4
    for (int e8 = 0; e8 < 128; e8 += 8) {
      union { uint16_t us[8]; uint4 v; } pk;
      pk.v = *(const uint4*)&fl[n * FLP + e0 + e8];
#pragma unroll
      for (int q = 0; q < 8; ++q) s += bf2f(pk.us[q]) * qk[e0 + e8 + q];
    }
    part[tid] = s;
  }
  __syncthreads();
  if (tid < 64) {
    float l = -1e30f;
    if (tid < 49)
      l = 0.044194173824159216f *
          (part[tid * 4] + part[tid * 4 + 1] + part[tid * 4 + 2] + part[tid * 4 + 3]);
    float mx = l;
#pragma unroll
    for (int o = 32; o > 0; o >>= 1) mx = fmaxf(mx, __shfl_xor(mx, o, 64));
    const float ex = (tid < 49) ? __expf(l - mx) : 0.f;
    float sm = ex;
#pragma unroll
    for (int o = 32; o > 0; o >>= 1) sm += __shfl_xor(sm, o, 64);
    if (tid < 49) attv[tid] = ex / sm;
  }
  __syncthreads();
  // fbar[e] = sum_n att[n] * feat[n][e]
  for (int e = tid; e < 512; e += 256) {
    float s = 0.f;
#pragma unroll 7
    for (int n = 0; n < 49; ++n) s += attv[n] * bf2f(fl[n * FLP + e]);
    fbar[e] = s;
  }
  __syncthreads();
  // v2[d] = p_b[d] + sum_e PVt[e][d] * fbar[e]
  for (int d = tid; d < 512; d += 256) {
    const float* P = PVt + ib * 262144 + d;
    float s = (ib ? pb2 : pb1)[d];
#pragma unroll 8
    for (int e = 0; e < 512; ++e) s += P[(size_t)e * 512] * fbar[e];
    v2[d] = s;
  }
  __syncthreads();
  // out[b][c][p] = feat[p][c] + v2[c]   (coalesced writes)
  float* ob = out + (size_t)ib * OUT1 + (size_t)b * 25088;
  for (int w = tid; w < 25088; w += 256) {
    const int c = w / 49, p = w - c * 49;
    ob[w] = bf2f(fl[p * FLP + c]) + v2[c];
  }
}

extern "C" void kernel_launch(void* const* d_in, const int* in_sizes, int n_in,
                              void* d_out, int out_size, void* d_ws, size_t ws_size,
                              hipStream_t stream) {
  const float* status = (const float*)d_in[0];
  const float* rois   = (const float*)d_in[1];
  const float* bbox   = (const float*)d_in[2];
  const float* convw  = (const float*)d_in[3];
  const float* q1w    = (const float*)d_in[4];
  const float* k1w    = (const float*)d_in[5];
  const float* k2w    = (const float*)d_in[6];
  const float* v1w    = (const float*)d_in[7];
  const float* v2w    = (const float*)d_in[8];
  const float* p1w    = (const float*)d_in[9];
  const float* p1b    = (const float*)d_in[10];
  const float* p2w    = (const float*)d_in[11];
  const float* p2b    = (const float*)d_in[12];
  float* out = (float*)d_out;
  char* ws = (char*)d_ws;
  // ws layout (bytes): xT 57,802,752 | Wt 21,233,664 | feat0 12,845,056
  //                    | feat1 12,845,056 | PVt 2,097,152 | A 24,576
  //                    total 106,848,256 (== proven budget)
  uint16_t* xT    = (uint16_t*)(ws);
  uint16_t* Wt    = (uint16_t*)(ws + 57802752);
  uint16_t* feat0 = (uint16_t*)(ws + 79036416);
  uint16_t* feat1 = (uint16_t*)(ws + 91881472);
  float*    PVt   = (float*)(ws + 104726528);
  float*    A     = (float*)(ws + 106823680);
  if (ws_size < 106848256) return;  // insufficient scratch -> fail cleanly

  hipLaunchKernelGGL(prep1_k, dim3(18432), dim3(256), 0, stream, bbox, convw, xT, Wt);
  hipLaunchKernelGGL(conv_k,  dim3(928),   dim3(256), 0, stream, xT, Wt, feat0, feat1,
                     q1w, k1w, k2w, v1w, v2w, p1w, p2w, A, PVt);
  hipLaunchKernelGGL(att_k,   dim3(512),   dim3(256), 0, stream, feat0, feat1,
                     status, rois, A, PVt, p1b, p2b, out);
}